// Round 4
// baseline (448.436 us; speedup 1.0000x reference)
//
#include <hip/hip_runtime.h>

// GRFExactAttention — bf16 MFMA pipeline.
// B=8 N=1024 C=768 H=12 D=64. Inputs/outputs f32; internals bf16 (f32 accum).
//
// Math plan:
//  qkvT[2304][8192] = w_qkvT @ xT     (NT GEMM: A=w_qkvT[2304][768], B'=x[8192][768])
//       rows 0..767=q' (relu+eps), 768..1535=k' (relu+eps), 1536..2303=v
//  qks[b][1024][1536] = M' @ q'k'     (M'[m][n] = 0.1*mask[n][m] + I; A shared over b)
//  attn[b*1024+n][h*64+d] = z_n * sum_m (q_s[n]·k_s[m]) * mask[n][m] * v[m][d]
//  out = attn @ w_out + b_out

typedef unsigned short u16;
typedef __attribute__((ext_vector_type(8))) short short8;
typedef __attribute__((ext_vector_type(4))) float f32x4;

#define MFMA(a, b, c) __builtin_amdgcn_mfma_f32_16x16x32_bf16((a), (b), (c), 0, 0, 0)

__device__ __forceinline__ u16 f2b(float f) {  // f32 -> bf16 RNE
    unsigned u = __builtin_bit_cast(unsigned, f);
    return (u16)((u + 0x7FFFu + ((u >> 16) & 1u)) >> 16);
}
__device__ __forceinline__ float b2f(u16 h) {
    unsigned u = ((unsigned)h) << 16;
    return __builtin_bit_cast(float, u);
}

// ---------------------------------------------------------------------------
// elementwise f32 -> bf16
// ---------------------------------------------------------------------------
__global__ __launch_bounds__(256) void k_conv(const float* __restrict__ in,
                                              u16* __restrict__ out, int n) {
    int i = (blockIdx.x * 256 + threadIdx.x) * 4;
    if (i + 3 < n) {
        float4 v = *reinterpret_cast<const float4*>(&in[i]);
        ushort4 o;
        o.x = f2b(v.x); o.y = f2b(v.y); o.z = f2b(v.z); o.w = f2b(v.w);
        *reinterpret_cast<ushort4*>(&out[i]) = o;
    }
}

// ---------------------------------------------------------------------------
// transpose-convert: out[c][r] = bf16(in[r][c]*alpha + (r==c)*delta)
// in: [R][Cc] f32 ; out: [Cc][R] bf16. Grid (Cc/32, R/32), 256 thr.
// ---------------------------------------------------------------------------
__global__ __launch_bounds__(256) void k_transconv(const float* __restrict__ in,
                                                   u16* __restrict__ out,
                                                   int R, int Cc, float alpha, float delta) {
    __shared__ float t[32][33];
    const int tx = threadIdx.x & 31, ty = threadIdx.x >> 5;  // ty 0..7
    const int r0 = blockIdx.y * 32, c0 = blockIdx.x * 32;
#pragma unroll
    for (int k = 0; k < 4; ++k)
        t[ty + 8 * k][tx] = in[(long)(r0 + ty + 8 * k) * Cc + c0 + tx];
    __syncthreads();
#pragma unroll
    for (int k = 0; k < 4; ++k) {
        const int c = c0 + ty + 8 * k, r = r0 + tx;
        float v = t[tx][ty + 8 * k] * alpha + ((r == c) ? delta : 0.f);
        out[(long)c * R + r] = f2b(v);
    }
}

// ---------------------------------------------------------------------------
// bf16 NT GEMM: C[M][N] = A[M][K] * B'[N][K]^T ; 128x128 tile, BK=32, 4 waves.
// MODE 0: relu+eps rows<1536, bf16 out (qkvT)
// MODE 1: bf16 out, per-z offsets (smoothing)
// MODE 2: f32 out + bias (final)
// ---------------------------------------------------------------------------
template <int MODE>
__global__ __launch_bounds__(256) void k_gemm(const u16* __restrict__ A,
                                              const u16* __restrict__ Bm,
                                              void* __restrict__ Cv,
                                              const float* __restrict__ bias,
                                              int M, int N, int K,
                                              int lda, int ldb, int ldc,
                                              long boffB, long boffC) {
    __shared__ u16 As[128][40];
    __shared__ u16 Bs[128][40];
    const int tid = threadIdx.x;
    const int lane = tid & 63, wid = tid >> 6;
    const int lo = lane & 15, hi = lane >> 4;
    const int wr = wid >> 1, wc = wid & 1;
    const int m0 = blockIdx.y * 128, n0 = blockIdx.x * 128;
    const u16* Bz = Bm + (long)blockIdx.z * boffB;
    const int srow = tid >> 1, skoff = (tid & 1) * 16;  // 32B staged per thread
    const u16* Ag = A + (long)(m0 + srow) * lda + skoff;
    const u16* Bg = Bz + (long)(n0 + srow) * ldb + skoff;

    f32x4 acc[4][4] = {};
    for (int k0 = 0; k0 < K; k0 += 32) {
        short8 a0 = *reinterpret_cast<const short8*>(Ag + k0);
        short8 a1 = *reinterpret_cast<const short8*>(Ag + k0 + 8);
        short8 b0 = *reinterpret_cast<const short8*>(Bg + k0);
        short8 b1 = *reinterpret_cast<const short8*>(Bg + k0 + 8);
        __syncthreads();
        *reinterpret_cast<short8*>(&As[srow][skoff]) = a0;
        *reinterpret_cast<short8*>(&As[srow][skoff + 8]) = a1;
        *reinterpret_cast<short8*>(&Bs[srow][skoff]) = b0;
        *reinterpret_cast<short8*>(&Bs[srow][skoff + 8]) = b1;
        __syncthreads();
        short8 af[4], bf_[4];
#pragma unroll
        for (int i = 0; i < 4; ++i)
            af[i] = *reinterpret_cast<const short8*>(&As[wr * 64 + i * 16 + lo][hi * 8]);
#pragma unroll
        for (int j = 0; j < 4; ++j)
            bf_[j] = *reinterpret_cast<const short8*>(&Bs[wc * 64 + j * 16 + lo][hi * 8]);
#pragma unroll
        for (int i = 0; i < 4; ++i)
#pragma unroll
            for (int j = 0; j < 4; ++j)
                acc[i][j] = MFMA(af[i], bf_[j], acc[i][j]);
    }

#pragma unroll
    for (int i = 0; i < 4; ++i)
#pragma unroll
        for (int j = 0; j < 4; ++j)
#pragma unroll
            for (int r = 0; r < 4; ++r) {
                const int m = m0 + wr * 64 + i * 16 + hi * 4 + r;
                const int n = n0 + wc * 64 + j * 16 + lo;
                float v = acc[i][j][r];
                if (MODE == 0) {
                    if (m < 1536) v = fmaxf(v, 0.f) + 1e-6f;
                    ((u16*)Cv)[(long)m * ldc + n] = f2b(v);
                } else if (MODE == 1) {
                    u16* Cz = (u16*)Cv + (long)blockIdx.z * boffC;
                    Cz[(long)m * ldc + n] = f2b(v);
                } else {
                    ((float*)Cv)[(long)m * ldc + n] = v + bias[n];
                }
            }
}

// ---------------------------------------------------------------------------
// Fused masked linear attention — barrier-free version.
// Block = 64 q-rows of one (b,h); 4 waves, wave w owns q-rows [w*16, w*16+16).
// All LDS is wave-private -> NO __syncthreads anywhere (waves run independent
// pipelines; global loads stay in flight across tile iterations).
// QK^T computed TRANSPOSED (S^T = K·Q^T) so each lane owns one q-row (n=lo):
//   - mask multiply becomes one float4 load per 16-m chunk,
//   - rowsum is a single in-lane accumulator + 2 shfl_xor,
//   - S stash to LDS is 4x packed 8B writes.
// ---------------------------------------------------------------------------
__global__ __launch_bounds__(256) void k_attn2(const u16* __restrict__ qks,
                                               const u16* __restrict__ qkvT,
                                               const float* __restrict__ mask,
                                               u16* __restrict__ attn) {
    __shared__ u16 Sb[4][16][72];   // [wave][n(=lo)][m] ; row stride 144B (16B-aligned)
    __shared__ float Zs[4][16];
    const int tid = threadIdx.x, wid = tid >> 6, lane = tid & 63;
    const int lo = lane & 15, hi = lane >> 4;
    const int n0 = blockIdx.x * 64;
    const int bh = blockIdx.y, b = bh / 12, h = bh % 12;
    const long qbase = (long)b * 1024 * 1536;
    const int nA = n0 + wid * 16 + lo;  // this lane's q-row

    // Q fragments (B-operand): lane holds Q[n=nA][k = kd*32 + hi*8 ..+8]
    short8 aq[2];
#pragma unroll
    for (int kd = 0; kd < 2; ++kd)
        aq[kd] = *reinterpret_cast<const short8*>(
            &qks[qbase + (long)nA * 1536 + h * 64 + kd * 32 + hi * 8]);

    f32x4 oacc[4] = {};
    float rsum = 0.f;
    const long vrowbase = (long)(1536 + h * 64) * 8192 + (long)b * 1024;
    const float* mrow = mask + (long)nA * 1024;

    for (int m0 = 0; m0 < 1024; m0 += 64) {
        // ---- issue ALL loads for this tile up front (no barriers to drain) ----
        short8 kf[4][2];  // A-operand K: rows m = m0+jm*16+lo, k = kd*32+hi*8
#pragma unroll
        for (int jm = 0; jm < 4; ++jm) {
            const long kr = qbase + (long)(m0 + jm * 16 + lo) * 1536 + 768 + h * 64;
            kf[jm][0] = *reinterpret_cast<const short8*>(&qks[kr + hi * 8]);
            kf[jm][1] = *reinterpret_cast<const short8*>(&qks[kr + 32 + hi * 8]);
        }
        float4 mv[4];  // mask[nA][m0+jm*16+hi*4 ..+3]
#pragma unroll
        for (int jm = 0; jm < 4; ++jm)
            mv[jm] = *reinterpret_cast<const float4*>(&mrow[m0 + jm * 16 + hi * 4]);
        short8 vf[2][4];  // B-operand V^T: rows d = jd*16+lo, cols m = m0+km*32+hi*8
#pragma unroll
        for (int km = 0; km < 2; ++km)
#pragma unroll
            for (int jd = 0; jd < 4; ++jd)
                vf[km][jd] = *reinterpret_cast<const short8*>(
                    &qkvT[vrowbase + (long)(jd * 16 + lo) * 8192 + m0 + km * 32 + hi * 8]);

        // ---- S^T tile: s[r] = S[n=lo-row][m = jm*16 + hi*4 + r] ----
#pragma unroll
        for (int jm = 0; jm < 4; ++jm) {
            f32x4 s = {};
            s = MFMA(kf[jm][0], aq[0], s);
            s = MFMA(kf[jm][1], aq[1], s);
            const u16 h0 = f2b(s[0] * mv[jm].x);
            const u16 h1 = f2b(s[1] * mv[jm].y);
            const u16 h2 = f2b(s[2] * mv[jm].z);
            const u16 h3 = f2b(s[3] * mv[jm].w);
            rsum += (b2f(h0) + b2f(h1)) + (b2f(h2) + b2f(h3));
            uint2 packed;
            packed.x = (unsigned)h0 | ((unsigned)h1 << 16);
            packed.y = (unsigned)h2 | ((unsigned)h3 << 16);
            *reinterpret_cast<uint2*>(&Sb[wid][lo][jm * 16 + hi * 4]) = packed;
        }
        // ---- PV: oacc[jd] += P(16n x 64m) @ V^T ----
#pragma unroll
        for (int km = 0; km < 2; ++km) {
            const short8 pa =
                *reinterpret_cast<const short8*>(&Sb[wid][lo][km * 32 + hi * 8]);
#pragma unroll
            for (int jd = 0; jd < 4; ++jd)
                oacc[jd] = MFMA(pa, vf[km][jd], oacc[jd]);
        }
    }

    // rowsum for q-row n=lo: reduce across the 4 hi-groups
    rsum += __shfl_xor(rsum, 16);
    rsum += __shfl_xor(rsum, 32);
    const float z = 1.f / (rsum + 1e-6f);
    if (hi == 0) Zs[wid][lo] = z;  // wave-private bounce: z keyed by n-offset

    const long obase = (long)(b * 1024) * 768 + h * 64;
#pragma unroll
    for (int jd = 0; jd < 4; ++jd)
#pragma unroll
        for (int r = 0; r < 4; ++r) {
            const int nr = n0 + wid * 16 + hi * 4 + r;
            attn[obase + (long)nr * 768 + jd * 16 + lo] =
                f2b(oacc[jd][r] * Zs[wid][hi * 4 + r]);
        }
}

// ---------------------------------------------------------------------------

extern "C" void kernel_launch(void* const* d_in, const int* in_sizes, int n_in,
                              void* d_out, int out_size, void* d_ws, size_t ws_size,
                              hipStream_t stream) {
    (void)in_sizes; (void)n_in; (void)out_size; (void)ws_size;
    const float* x     = (const float*)d_in[0];
    const float* mask  = (const float*)d_in[1];
    const float* w_qkv = (const float*)d_in[2];
    const float* w_out = (const float*)d_in[3];
    const float* b_out = (const float*)d_in[4];
    float* out = (float*)d_out;

    u16* ws = (u16*)d_ws;  // element (2B) offsets
    u16* xb     = ws;                       // [8192][768]
    u16* wqkvT  = xb + (size_t)8192 * 768;  // [2304][768]
    u16* mTb    = wqkvT + (size_t)2304 * 768;   // [1024][1024]
    u16* woutT  = mTb + (size_t)1024 * 1024;    // [768][768]
    u16* qkvT   = woutT + (size_t)768 * 768;    // [2304][8192]
    u16* qks    = qkvT + (size_t)2304 * 8192;   // [8][1024][1536]
    u16* attnb  = qks + (size_t)8192 * 1536;    // [8192][768]

    // conversions / transposes
    k_conv<<<dim3(6144), dim3(256), 0, stream>>>(x, xb, 8192 * 768);
    k_transconv<<<dim3(72, 24), dim3(256), 0, stream>>>(w_qkv, wqkvT, 768, 2304, 1.f, 0.f);
    k_transconv<<<dim3(32, 32), dim3(256), 0, stream>>>(mask, mTb, 1024, 1024, 0.1f, 1.f);
    k_transconv<<<dim3(24, 24), dim3(256), 0, stream>>>(w_out, woutT, 768, 768, 1.f, 0.f);

    // qkvT = w_qkvT @ xT (relu+eps on q,k rows)
    k_gemm<0><<<dim3(64, 18, 1), dim3(256), 0, stream>>>(
        wqkvT, xb, qkvT, nullptr, 2304, 8192, 768, 768, 768, 8192, 0, 0);
    // qks[b] = M' @ [q'|k']  (per batch)
    k_gemm<1><<<dim3(12, 8, 8), dim3(256), 0, stream>>>(
        mTb, qkvT, qks, nullptr, 1024, 1536, 1024, 1024, 8192, 1536,
        1024L, 1024L * 1536L);
    // fused attention
    k_attn2<<<dim3(16, 96), dim3(256), 0, stream>>>(qks, qkvT, mask, attnb);
    // out = attn @ w_out + b_out
    k_gemm<2><<<dim3(6, 64, 1), dim3(256), 0, stream>>>(
        attnb, woutT, out, b_out, 8192, 768, 768, 768, 768, 768, 0, 0);
}

// Round 5
// 273.233 us; speedup vs baseline: 1.6412x; 1.6412x over previous
//
#include <hip/hip_runtime.h>

// GRFExactAttention — bf16 MFMA pipeline, LDS-staged attention.
// B=8 N=1024 C=768 H=12 D=64. Inputs/outputs f32; internals bf16 (f32 accum).

typedef unsigned short u16;
typedef unsigned int u32;
typedef __attribute__((ext_vector_type(8))) short short8;
typedef __attribute__((ext_vector_type(4))) float f32x4;

#define MFMA(a, b, c) __builtin_amdgcn_mfma_f32_16x16x32_bf16((a), (b), (c), 0, 0, 0)

__device__ __forceinline__ u16 f2b(float f) {  // f32 -> bf16 RNE
    unsigned u = __builtin_bit_cast(unsigned, f);
    return (u16)((u + 0x7FFFu + ((u >> 16) & 1u)) >> 16);
}
__device__ __forceinline__ float b2f(u16 h) {
    unsigned u = ((unsigned)h) << 16;
    return __builtin_bit_cast(float, u);
}
// async global->LDS, 16B per lane; lds dest must be wave-uniform base.
__device__ __forceinline__ void gl_lds16(const u16* g, u16* l) {
    __builtin_amdgcn_global_load_lds(
        (const __attribute__((address_space(1))) u32*)g,
        (__attribute__((address_space(3))) u32*)l, 16, 0, 0);
}

// ---------------------------------------------------------------------------
// elementwise f32 -> bf16
// ---------------------------------------------------------------------------
__global__ __launch_bounds__(256) void k_conv(const float* __restrict__ in,
                                              u16* __restrict__ out, int n) {
    int i = (blockIdx.x * 256 + threadIdx.x) * 4;
    if (i + 3 < n) {
        float4 v = *reinterpret_cast<const float4*>(&in[i]);
        ushort4 o;
        o.x = f2b(v.x); o.y = f2b(v.y); o.z = f2b(v.z); o.w = f2b(v.w);
        *reinterpret_cast<ushort4*>(&out[i]) = o;
    }
}

// ---------------------------------------------------------------------------
// transpose-convert: out[c][r] = bf16(in[r][c]*alpha + (r==c)*delta)
// ---------------------------------------------------------------------------
__global__ __launch_bounds__(256) void k_transconv(const float* __restrict__ in,
                                                   u16* __restrict__ out,
                                                   int R, int Cc, float alpha, float delta) {
    __shared__ float t[32][33];
    const int tx = threadIdx.x & 31, ty = threadIdx.x >> 5;
    const int r0 = blockIdx.y * 32, c0 = blockIdx.x * 32;
#pragma unroll
    for (int k = 0; k < 4; ++k)
        t[ty + 8 * k][tx] = in[(long)(r0 + ty + 8 * k) * Cc + c0 + tx];
    __syncthreads();
#pragma unroll
    for (int k = 0; k < 4; ++k) {
        const int c = c0 + ty + 8 * k, r = r0 + tx;
        float v = t[tx][ty + 8 * k] * alpha + ((r == c) ? delta : 0.f);
        out[(long)c * R + r] = f2b(v);
    }
}

// ---------------------------------------------------------------------------
// bf16 NT GEMM: C[M][N] = A[M][K] * B'[N][K]^T ; 128x128 tile, BK=32, 4 waves.
// (unchanged from round 3)
// ---------------------------------------------------------------------------
template <int MODE>
__global__ __launch_bounds__(256) void k_gemm(const u16* __restrict__ A,
                                              const u16* __restrict__ Bm,
                                              void* __restrict__ Cv,
                                              const float* __restrict__ bias,
                                              int M, int N, int K,
                                              int lda, int ldb, int ldc,
                                              long boffB, long boffC) {
    __shared__ u16 As[128][40];
    __shared__ u16 Bs[128][40];
    const int tid = threadIdx.x;
    const int lane = tid & 63, wid = tid >> 6;
    const int lo = lane & 15, hi = lane >> 4;
    const int wr = wid >> 1, wc = wid & 1;
    const int m0 = blockIdx.y * 128, n0 = blockIdx.x * 128;
    const u16* Bz = Bm + (long)blockIdx.z * boffB;
    const int srow = tid >> 1, skoff = (tid & 1) * 16;
    const u16* Ag = A + (long)(m0 + srow) * lda + skoff;
    const u16* Bg = Bz + (long)(n0 + srow) * ldb + skoff;

    f32x4 acc[4][4] = {};
    for (int k0 = 0; k0 < K; k0 += 32) {
        short8 a0 = *reinterpret_cast<const short8*>(Ag + k0);
        short8 a1 = *reinterpret_cast<const short8*>(Ag + k0 + 8);
        short8 b0 = *reinterpret_cast<const short8*>(Bg + k0);
        short8 b1 = *reinterpret_cast<const short8*>(Bg + k0 + 8);
        __syncthreads();
        *reinterpret_cast<short8*>(&As[srow][skoff]) = a0;
        *reinterpret_cast<short8*>(&As[srow][skoff + 8]) = a1;
        *reinterpret_cast<short8*>(&Bs[srow][skoff]) = b0;
        *reinterpret_cast<short8*>(&Bs[srow][skoff + 8]) = b1;
        __syncthreads();
        short8 af[4], bf_[4];
#pragma unroll
        for (int i = 0; i < 4; ++i)
            af[i] = *reinterpret_cast<const short8*>(&As[wr * 64 + i * 16 + lo][hi * 8]);
#pragma unroll
        for (int j = 0; j < 4; ++j)
            bf_[j] = *reinterpret_cast<const short8*>(&Bs[wc * 64 + j * 16 + lo][hi * 8]);
#pragma unroll
        for (int i = 0; i < 4; ++i)
#pragma unroll
            for (int j = 0; j < 4; ++j)
                acc[i][j] = MFMA(af[i], bf_[j], acc[i][j]);
    }

#pragma unroll
    for (int i = 0; i < 4; ++i)
#pragma unroll
        for (int j = 0; j < 4; ++j)
#pragma unroll
            for (int r = 0; r < 4; ++r) {
                const int m = m0 + wr * 64 + i * 16 + hi * 4 + r;
                const int n = n0 + wc * 64 + j * 16 + lo;
                float v = acc[i][j][r];
                if (MODE == 0) {
                    if (m < 1536) v = fmaxf(v, 0.f) + 1e-6f;
                    ((u16*)Cv)[(long)m * ldc + n] = f2b(v);
                } else if (MODE == 1) {
                    u16* Cz = (u16*)Cv + (long)blockIdx.z * boffC;
                    Cz[(long)m * ldc + n] = f2b(v);
                } else {
                    ((float*)Cv)[(long)m * ldc + n] = v + bias[n];
                }
            }
}

// ---------------------------------------------------------------------------
// Fused masked linear attention, LDS-staged + double-buffered.
// Block = 128 q-rows of one (b,h); 4 waves; wave owns 32 q-rows (2 subgroups
// of 16). Per 64-key tile: K[64m][64k] and V^T[64d][64m] staged to LDS via
// global_load_lds (linear dest, XOR-swizzled SOURCE per rule 21); mask read
// per-lane from a bf16 copy. 2-phase pipeline: STAGE(next) -> compute(cur)
// -> syncthreads.
// LDS read swizzle: row r, logical 16B chunk c lives at chunk (c ^ (r&7)).
// ---------------------------------------------------------------------------
__global__ __launch_bounds__(256) void k_attn2(const u16* __restrict__ qks,
                                               const u16* __restrict__ qkvT,
                                               const u16* __restrict__ mb,
                                               u16* __restrict__ attn) {
    __shared__ u16 Ks[2][64][64];   // [buf][m][k] rows 128B, swizzled
    __shared__ u16 Vt[2][64][64];   // [buf][d][m] rows 128B, swizzled
    __shared__ u16 Sb[4][16][72];   // per-wave P stash (reused across qg)
    __shared__ float Zs[4][2][16];
    const int tid = threadIdx.x, wid = tid >> 6, lane = tid & 63;
    const int lo = lane & 15, hi = lane >> 4;
    const int n0 = blockIdx.x * 128;
    const int bh = blockIdx.y, b = bh / 12, h = bh % 12;
    const long qbase = (long)b * 1024 * 1536;

    // ---- Q fragments (held in registers for the whole kernel) ----
    short8 aq[2][2];
#pragma unroll
    for (int qg = 0; qg < 2; ++qg)
#pragma unroll
        for (int kd = 0; kd < 2; ++kd)
            aq[qg][kd] = *reinterpret_cast<const short8*>(
                &qks[qbase + (long)(n0 + wid * 32 + qg * 16 + lo) * 1536 + h * 64 +
                     kd * 32 + hi * 8]);

    // ---- staging source pointers (pre-swizzled global, linear LDS dest) ----
    // wave wid stages LDS rows [wid*16, wid*16+16), instr i covers 8 rows.
    const u16* gK[2];
    const u16* gV[2];
    int ldsrow[2];
#pragma unroll
    for (int i = 0; i < 2; ++i) {
        const int r = wid * 16 + i * 8 + (lane >> 3);       // tile row this lane fills
        const int cs = (lane & 7) ^ (r & 7);                // swizzled source chunk
        ldsrow[i] = wid * 16 + i * 8;
        gK[i] = qks + qbase + (long)r * 1536 + 768 + h * 64 + cs * 8;
        gV[i] = qkvT + (long)(1536 + h * 64 + r) * 8192 + (long)b * 1024 + cs * 8;
    }

    const u16* mrow[2];
#pragma unroll
    for (int qg = 0; qg < 2; ++qg)
        mrow[qg] = mb + (long)(n0 + wid * 32 + qg * 16 + lo) * 1024;

    f32x4 oacc[2][4] = {};
    float rsum[2] = {0.f, 0.f};

    // ---- prologue: stage tile 0 into buf 0 ----
#pragma unroll
    for (int i = 0; i < 2; ++i) {
        gl_lds16(gK[i], &Ks[0][ldsrow[i]][0]);
        gl_lds16(gV[i], &Vt[0][ldsrow[i]][0]);
    }
    __syncthreads();

    for (int t = 0; t < 16; ++t) {
        const int cur = t & 1;
        if (t < 15) {  // stage next tile into the other buffer (async)
            const long m1 = (long)(t + 1) * 64;
#pragma unroll
            for (int i = 0; i < 2; ++i) {
                gl_lds16(gK[i] + m1 * 1536, &Ks[cur ^ 1][ldsrow[i]][0]);
                gl_lds16(gV[i] + m1, &Vt[cur ^ 1][ldsrow[i]][0]);
            }
        }
        // K fragments from LDS (shared across both q-subgroups)
        short8 kfr[4][2];
#pragma unroll
        for (int jm = 0; jm < 4; ++jm)
#pragma unroll
            for (int kd = 0; kd < 2; ++kd)
                kfr[jm][kd] = *reinterpret_cast<const short8*>(
                    &Ks[cur][jm * 16 + lo][(((kd * 4 + hi) ^ (lo & 7))) * 8]);

#pragma unroll
        for (int qg = 0; qg < 2; ++qg) {
            // S^T tile: lane owns q-row n = qg*16+lo (local), m = jm*16+hi*4+r
            f32x4 s[4];
#pragma unroll
            for (int jm = 0; jm < 4; ++jm) {
                f32x4 sj = {};
                sj = MFMA(kfr[jm][0], aq[qg][0], sj);
                sj = MFMA(kfr[jm][1], aq[qg][1], sj);
                s[jm] = sj;
            }
            // mask (bf16) multiply + rowsum + stash to wave-private LDS
#pragma unroll
            for (int jm = 0; jm < 4; ++jm) {
                ushort4 mv = *reinterpret_cast<const ushort4*>(
                    &mrow[qg][t * 64 + jm * 16 + hi * 4]);
                const u16 h0 = f2b(s[jm][0] * b2f(mv.x));
                const u16 h1 = f2b(s[jm][1] * b2f(mv.y));
                const u16 h2 = f2b(s[jm][2] * b2f(mv.z));
                const u16 h3 = f2b(s[jm][3] * b2f(mv.w));
                rsum[qg] += (b2f(h0) + b2f(h1)) + (b2f(h2) + b2f(h3));
                uint2 packed;
                packed.x = (u32)h0 | ((u32)h1 << 16);
                packed.y = (u32)h2 | ((u32)h3 << 16);
                *reinterpret_cast<uint2*>(&Sb[wid][lo][jm * 16 + hi * 4]) = packed;
            }
            // PV: oacc[qg][jd] += P(16n x 64m) @ V^T
#pragma unroll
            for (int km = 0; km < 2; ++km) {
                const short8 pa =
                    *reinterpret_cast<const short8*>(&Sb[wid][lo][km * 32 + hi * 8]);
#pragma unroll
                for (int jd = 0; jd < 4; ++jd) {
                    const short8 vfr = *reinterpret_cast<const short8*>(
                        &Vt[cur][jd * 16 + lo][(((km * 4 + hi) ^ (lo & 7))) * 8]);
                    oacc[qg][jd] = MFMA(pa, vfr, oacc[qg][jd]);
                }
            }
        }
        __syncthreads();  // next-tile staging complete; cur free for overwrite
    }

    // ---- z and epilogue ----
#pragma unroll
    for (int qg = 0; qg < 2; ++qg) {
        float v = rsum[qg];
        v += __shfl_xor(v, 16);
        v += __shfl_xor(v, 32);
        if (hi == 0) Zs[wid][qg][lo] = 1.f / (v + 1e-6f);
    }
    const long obase = (long)(b * 1024) * 768 + h * 64;
#pragma unroll
    for (int qg = 0; qg < 2; ++qg)
#pragma unroll
        for (int jd = 0; jd < 4; ++jd)
#pragma unroll
            for (int r = 0; r < 4; ++r) {
                const int nr = n0 + wid * 32 + qg * 16 + hi * 4 + r;
                attn[obase + (long)nr * 768 + jd * 16 + lo] =
                    f2b(oacc[qg][jd][r] * Zs[wid][qg][hi * 4 + r]);
            }
}

// ---------------------------------------------------------------------------

extern "C" void kernel_launch(void* const* d_in, const int* in_sizes, int n_in,
                              void* d_out, int out_size, void* d_ws, size_t ws_size,
                              hipStream_t stream) {
    (void)in_sizes; (void)n_in; (void)out_size; (void)ws_size;
    const float* x     = (const float*)d_in[0];
    const float* mask  = (const float*)d_in[1];
    const float* w_qkv = (const float*)d_in[2];
    const float* w_out = (const float*)d_in[3];
    const float* b_out = (const float*)d_in[4];
    float* out = (float*)d_out;

    u16* ws = (u16*)d_ws;  // element (2B) offsets
    u16* xb     = ws;                           // [8192][768]
    u16* wqkvT  = xb + (size_t)8192 * 768;      // [2304][768]
    u16* mTb    = wqkvT + (size_t)2304 * 768;   // [1024][1024]
    u16* woutT  = mTb + (size_t)1024 * 1024;    // [768][768]
    u16* qkvT   = woutT + (size_t)768 * 768;    // [2304][8192]
    u16* qks    = qkvT + (size_t)2304 * 8192;   // [8][1024][1536]
    u16* attnb  = qks + (size_t)8192 * 1536;    // [8192][768]
    u16* mbb    = attnb + (size_t)8192 * 768;   // [1024][1024] bf16 mask

    // conversions / transposes
    k_conv<<<dim3(6144), dim3(256), 0, stream>>>(x, xb, 8192 * 768);
    k_conv<<<dim3(1024), dim3(256), 0, stream>>>(mask, mbb, 1024 * 1024);
    k_transconv<<<dim3(72, 24), dim3(256), 0, stream>>>(w_qkv, wqkvT, 768, 2304, 1.f, 0.f);
    k_transconv<<<dim3(32, 32), dim3(256), 0, stream>>>(mask, mTb, 1024, 1024, 0.1f, 1.f);
    k_transconv<<<dim3(24, 24), dim3(256), 0, stream>>>(w_out, woutT, 768, 768, 1.f, 0.f);

    // qkvT = w_qkvT @ xT (relu+eps on q,k rows)
    k_gemm<0><<<dim3(64, 18, 1), dim3(256), 0, stream>>>(
        wqkvT, xb, qkvT, nullptr, 2304, 8192, 768, 768, 768, 8192, 0, 0);
    // qks[b] = M' @ [q'|k']  (per batch)
    k_gemm<1><<<dim3(12, 8, 8), dim3(256), 0, stream>>>(
        mTb, qkvT, qks, nullptr, 1024, 1536, 1024, 1024, 8192, 1536,
        1024L, 1024L * 1536L);
    // fused attention
    k_attn2<<<dim3(8, 96), dim3(256), 0, stream>>>(qks, qkvT, mbb, attnb);
    // out = attn @ w_out + b_out
    k_gemm<2><<<dim3(6, 64, 1), dim3(256), 0, stream>>>(
        attnb, woutT, out, b_out, 8192, 768, 768, 768, 768, 768, 0, 0);
}

// Round 6
// 265.987 us; speedup vs baseline: 1.6859x; 1.0272x over previous
//
#include <hip/hip_runtime.h>

// GRFExactAttention — bf16 MFMA pipeline, LDS-staged attention + m97-style GEMMs.
// B=8 N=1024 C=768 H=12 D=64. Inputs/outputs f32; internals bf16 (f32 accum).

typedef unsigned short u16;
typedef unsigned int u32;
typedef __attribute__((ext_vector_type(8))) short short8;
typedef __attribute__((ext_vector_type(4))) float f32x4;

#define MFMA(a, b, c) __builtin_amdgcn_mfma_f32_16x16x32_bf16((a), (b), (c), 0, 0, 0)

__device__ __forceinline__ u16 f2b(float f) {  // f32 -> bf16 RNE
    unsigned u = __builtin_bit_cast(unsigned, f);
    return (u16)((u + 0x7FFFu + ((u >> 16) & 1u)) >> 16);
}
__device__ __forceinline__ float b2f(u16 h) {
    unsigned u = ((unsigned)h) << 16;
    return __builtin_bit_cast(float, u);
}
// pack 2 f32 -> 1 u32 holding 2 bf16 (lo=a, hi=b), hardware RNE
__device__ __forceinline__ u32 cvt_pk_bf16(float a, float b) {
    u32 r;
    asm("v_cvt_pk_bf16_f32 %0, %1, %2" : "=v"(r) : "v"(a), "v"(b));
    return r;
}
// async global->LDS, 16B per lane; lds dest must be wave-uniform base.
__device__ __forceinline__ void gl_lds16(const u16* g, u16* l) {
    __builtin_amdgcn_global_load_lds(
        (const __attribute__((address_space(1))) u32*)g,
        (__attribute__((address_space(3))) u32*)l, 16, 0, 0);
}

// ---------------------------------------------------------------------------
// elementwise f32 -> bf16
// ---------------------------------------------------------------------------
__global__ __launch_bounds__(256) void k_conv(const float* __restrict__ in,
                                              u16* __restrict__ out, int n) {
    int i = (blockIdx.x * 256 + threadIdx.x) * 4;
    if (i + 3 < n) {
        float4 v = *reinterpret_cast<const float4*>(&in[i]);
        ushort4 o;
        o.x = f2b(v.x); o.y = f2b(v.y); o.z = f2b(v.z); o.w = f2b(v.w);
        *reinterpret_cast<ushort4*>(&out[i]) = o;
    }
}

// ---------------------------------------------------------------------------
// transpose-convert: out[c][r] = bf16(in[r][c]*alpha + (r==c)*delta)
// ---------------------------------------------------------------------------
__global__ __launch_bounds__(256) void k_transconv(const float* __restrict__ in,
                                                   u16* __restrict__ out,
                                                   int R, int Cc, float alpha, float delta) {
    __shared__ float t[32][33];
    const int tx = threadIdx.x & 31, ty = threadIdx.x >> 5;
    const int r0 = blockIdx.y * 32, c0 = blockIdx.x * 32;
#pragma unroll
    for (int k = 0; k < 4; ++k)
        t[ty + 8 * k][tx] = in[(long)(r0 + ty + 8 * k) * Cc + c0 + tx];
    __syncthreads();
#pragma unroll
    for (int k = 0; k < 4; ++k) {
        const int c = c0 + ty + 8 * k, r = r0 + tx;
        float v = t[tx][ty + 8 * k] * alpha + ((r == c) ? delta : 0.f);
        out[(long)c * R + r] = f2b(v);
    }
}

// ---------------------------------------------------------------------------
// bf16 NT GEMM, m97 structure: C[M][N] = A[M][K] * B'[N][K]^T
// 128x128 tile, BK=32, 4 waves, global_load_lds width-16 staging into
// LINEAR LDS [128][32] (64B rows; wave-uniform dest + lane*16B).
// MODE 0: relu+eps rows<1536, bf16 out (qkvT)
// MODE 1: bf16 out, per-z offsets (smoothing)
// MODE 2: f32 out + bias (final)
// ---------------------------------------------------------------------------
template <int MODE>
__global__ __launch_bounds__(256) void k_gemm(const u16* __restrict__ A,
                                              const u16* __restrict__ Bm,
                                              void* __restrict__ Cv,
                                              const float* __restrict__ bias,
                                              int M, int N, int K,
                                              int lda, int ldb, int ldc,
                                              long boffB, long boffC) {
    __shared__ u16 As[128 * 32];
    __shared__ u16 Bs[128 * 32];
    const int tid = threadIdx.x;
    const int lane = tid & 63, wid = tid >> 6;
    const int lo = lane & 15, hi = lane >> 4;
    const int wr = wid >> 1, wc = wid & 1;
    const int m0 = blockIdx.y * 128, n0 = blockIdx.x * 128;
    const u16* Bz = Bm + (long)blockIdx.z * boffB;

    // staging: wave wid covers tile rows [wid*32, wid*32+32), 2 instrs of 16 rows;
    // lane l fills row +(l>>2), 16B chunk (l&3).
    const int rA = wid * 32 + (lane >> 2);
    const int ck = (lane & 3) * 8;  // element offset in row
    const u16* Ag = A + (long)(m0 + rA) * lda + ck;
    const u16* Bg = Bz + (long)(n0 + rA) * ldb + ck;
    u16* AsW = As + (wid * 32) * 32;
    u16* BsW = Bs + (wid * 32) * 32;

    f32x4 acc[4][4] = {};
    for (int k0 = 0; k0 < K; k0 += 32) {
        __syncthreads();  // previous iteration's ds_reads done -> safe to overwrite
#pragma unroll
        for (int i = 0; i < 2; ++i) {
            gl_lds16(Ag + (long)i * 16 * lda + k0, AsW + i * 16 * 32);
            gl_lds16(Bg + (long)i * 16 * ldb + k0, BsW + i * 16 * 32);
        }
        __syncthreads();  // staging visible (vmcnt drained by barrier)
        short8 af[4], bf_[4];
#pragma unroll
        for (int i = 0; i < 4; ++i)
            af[i] = *reinterpret_cast<const short8*>(&As[(wr * 64 + i * 16 + lo) * 32 + hi * 8]);
#pragma unroll
        for (int j = 0; j < 4; ++j)
            bf_[j] = *reinterpret_cast<const short8*>(&Bs[(wc * 64 + j * 16 + lo) * 32 + hi * 8]);
#pragma unroll
        for (int i = 0; i < 4; ++i)
#pragma unroll
            for (int j = 0; j < 4; ++j)
                acc[i][j] = MFMA(af[i], bf_[j], acc[i][j]);
    }

#pragma unroll
    for (int i = 0; i < 4; ++i)
#pragma unroll
        for (int j = 0; j < 4; ++j)
#pragma unroll
            for (int r = 0; r < 4; ++r) {
                const int m = m0 + wr * 64 + i * 16 + hi * 4 + r;
                const int n = n0 + wc * 64 + j * 16 + lo;
                float v = acc[i][j][r];
                if (MODE == 0) {
                    if (m < 1536) v = fmaxf(v, 0.f) + 1e-6f;
                    ((u16*)Cv)[(long)m * ldc + n] = f2b(v);
                } else if (MODE == 1) {
                    u16* Cz = (u16*)Cv + (long)blockIdx.z * boffC;
                    Cz[(long)m * ldc + n] = f2b(v);
                } else {
                    ((float*)Cv)[(long)m * ldc + n] = v + bias[n];
                }
            }
}

// ---------------------------------------------------------------------------
// Fused masked linear attention, LDS-staged + double-buffered.
// Block = 128 q-rows of one (b,h); 4 waves; wave owns 32 q-rows (2 subgroups
// of 16). K[64m][64k] and V^T[64d][64m] staged via global_load_lds (linear
// dest, XOR-swizzled SOURCE); mask from bf16 copy. S-epilogue uses
// v_cvt_pk_bf16_f32; rowsum from unrounded f32 products.
// ---------------------------------------------------------------------------
__global__ __launch_bounds__(256) void k_attn2(const u16* __restrict__ qks,
                                               const u16* __restrict__ qkvT,
                                               const u16* __restrict__ mb,
                                               u16* __restrict__ attn) {
    __shared__ u16 Ks[2][64][64];   // [buf][m][k] rows 128B, chunk-swizzled
    __shared__ u16 Vt[2][64][64];   // [buf][d][m] rows 128B, chunk-swizzled
    __shared__ u16 Sb[4][16][72];   // per-wave P stash
    __shared__ float Zs[4][2][16];
    const int tid = threadIdx.x, wid = tid >> 6, lane = tid & 63;
    const int lo = lane & 15, hi = lane >> 4;
    const int n0 = blockIdx.x * 128;
    const int bh = blockIdx.y, b = bh / 12, h = bh % 12;
    const long qbase = (long)b * 1024 * 1536;

    // ---- Q fragments (registers, whole kernel) ----
    short8 aq[2][2];
#pragma unroll
    for (int qg = 0; qg < 2; ++qg)
#pragma unroll
        for (int kd = 0; kd < 2; ++kd)
            aq[qg][kd] = *reinterpret_cast<const short8*>(
                &qks[qbase + (long)(n0 + wid * 32 + qg * 16 + lo) * 1536 + h * 64 +
                     kd * 32 + hi * 8]);

    // ---- staging source pointers (pre-swizzled global, linear LDS dest) ----
    const u16* gK[2];
    const u16* gV[2];
    int ldsrow[2];
#pragma unroll
    for (int i = 0; i < 2; ++i) {
        const int r = wid * 16 + i * 8 + (lane >> 3);
        const int cs = (lane & 7) ^ (r & 7);
        ldsrow[i] = wid * 16 + i * 8;
        gK[i] = qks + qbase + (long)r * 1536 + 768 + h * 64 + cs * 8;
        gV[i] = qkvT + (long)(1536 + h * 64 + r) * 8192 + (long)b * 1024 + cs * 8;
    }

    const u16* mrow[2];
#pragma unroll
    for (int qg = 0; qg < 2; ++qg)
        mrow[qg] = mb + (long)(n0 + wid * 32 + qg * 16 + lo) * 1024;

    f32x4 oacc[2][4] = {};
    float rsum[2] = {0.f, 0.f};

    // ---- prologue: stage tile 0 ----
#pragma unroll
    for (int i = 0; i < 2; ++i) {
        gl_lds16(gK[i], &Ks[0][ldsrow[i]][0]);
        gl_lds16(gV[i], &Vt[0][ldsrow[i]][0]);
    }
    __syncthreads();

    for (int t = 0; t < 16; ++t) {
        const int cur = t & 1;
        if (t < 15) {
            const long m1 = (long)(t + 1) * 64;
#pragma unroll
            for (int i = 0; i < 2; ++i) {
                gl_lds16(gK[i] + m1 * 1536, &Ks[cur ^ 1][ldsrow[i]][0]);
                gl_lds16(gV[i] + m1, &Vt[cur ^ 1][ldsrow[i]][0]);
            }
        }
        short8 kfr[4][2];
#pragma unroll
        for (int jm = 0; jm < 4; ++jm)
#pragma unroll
            for (int kd = 0; kd < 2; ++kd)
                kfr[jm][kd] = *reinterpret_cast<const short8*>(
                    &Ks[cur][jm * 16 + lo][(((kd * 4 + hi) ^ (lo & 7))) * 8]);

#pragma unroll
        for (int qg = 0; qg < 2; ++qg) {
            f32x4 s[4];
#pragma unroll
            for (int jm = 0; jm < 4; ++jm) {
                f32x4 sj = {};
                sj = MFMA(kfr[jm][0], aq[qg][0], sj);
                sj = MFMA(kfr[jm][1], aq[qg][1], sj);
                s[jm] = sj;
            }
#pragma unroll
            for (int jm = 0; jm < 4; ++jm) {
                ushort4 mv = *reinterpret_cast<const ushort4*>(
                    &mrow[qg][t * 64 + jm * 16 + hi * 4]);
                const float p0 = s[jm][0] * b2f(mv.x);
                const float p1 = s[jm][1] * b2f(mv.y);
                const float p2 = s[jm][2] * b2f(mv.z);
                const float p3 = s[jm][3] * b2f(mv.w);
                rsum[qg] += (p0 + p1) + (p2 + p3);
                uint2 packed;
                packed.x = cvt_pk_bf16(p0, p1);
                packed.y = cvt_pk_bf16(p2, p3);
                *reinterpret_cast<uint2*>(&Sb[wid][lo][jm * 16 + hi * 4]) = packed;
            }
#pragma unroll
            for (int km = 0; km < 2; ++km) {
                const short8 pa =
                    *reinterpret_cast<const short8*>(&Sb[wid][lo][km * 32 + hi * 8]);
#pragma unroll
                for (int jd = 0; jd < 4; ++jd) {
                    const short8 vfr = *reinterpret_cast<const short8*>(
                        &Vt[cur][jd * 16 + lo][(((km * 4 + hi) ^ (lo & 7))) * 8]);
                    oacc[qg][jd] = MFMA(pa, vfr, oacc[qg][jd]);
                }
            }
        }
        __syncthreads();
    }

    // ---- z and epilogue ----
#pragma unroll
    for (int qg = 0; qg < 2; ++qg) {
        float v = rsum[qg];
        v += __shfl_xor(v, 16);
        v += __shfl_xor(v, 32);
        if (hi == 0) Zs[wid][qg][lo] = 1.f / (v + 1e-6f);
    }
    const long obase = (long)(b * 1024) * 768 + h * 64;
#pragma unroll
    for (int qg = 0; qg < 2; ++qg)
#pragma unroll
        for (int jd = 0; jd < 4; ++jd)
#pragma unroll
            for (int r = 0; r < 4; ++r) {
                const int nr = n0 + wid * 32 + qg * 16 + hi * 4 + r;
                attn[obase + (long)nr * 768 + jd * 16 + lo] =
                    f2b(oacc[qg][jd][r] * Zs[wid][qg][hi * 4 + r]);
            }
}

// ---------------------------------------------------------------------------

extern "C" void kernel_launch(void* const* d_in, const int* in_sizes, int n_in,
                              void* d_out, int out_size, void* d_ws, size_t ws_size,
                              hipStream_t stream) {
    (void)in_sizes; (void)n_in; (void)out_size; (void)ws_size;
    const float* x     = (const float*)d_in[0];
    const float* mask  = (const float*)d_in[1];
    const float* w_qkv = (const float*)d_in[2];
    const float* w_out = (const float*)d_in[3];
    const float* b_out = (const float*)d_in[4];
    float* out = (float*)d_out;

    u16* ws = (u16*)d_ws;  // element (2B) offsets
    u16* xb     = ws;                           // [8192][768]
    u16* wqkvT  = xb + (size_t)8192 * 768;      // [2304][768]
    u16* mTb    = wqkvT + (size_t)2304 * 768;   // [1024][1024]
    u16* woutT  = mTb + (size_t)1024 * 1024;    // [768][768]
    u16* qkvT   = woutT + (size_t)768 * 768;    // [2304][8192]
    u16* qks    = qkvT + (size_t)2304 * 8192;   // [8][1024][1536]
    u16* attnb  = qks + (size_t)8192 * 1536;    // [8192][768]
    u16* mbb    = attnb + (size_t)8192 * 768;   // [1024][1024] bf16 mask

    // conversions / transposes
    k_conv<<<dim3(6144), dim3(256), 0, stream>>>(x, xb, 8192 * 768);
    k_conv<<<dim3(1024), dim3(256), 0, stream>>>(mask, mbb, 1024 * 1024);
    k_transconv<<<dim3(72, 24), dim3(256), 0, stream>>>(w_qkv, wqkvT, 768, 2304, 1.f, 0.f);
    k_transconv<<<dim3(32, 32), dim3(256), 0, stream>>>(mask, mTb, 1024, 1024, 0.1f, 1.f);
    k_transconv<<<dim3(24, 24), dim3(256), 0, stream>>>(w_out, woutT, 768, 768, 1.f, 0.f);

    // qkvT = w_qkvT @ xT (relu+eps on q,k rows)
    k_gemm<0><<<dim3(64, 18, 1), dim3(256), 0, stream>>>(
        wqkvT, xb, qkvT, nullptr, 2304, 8192, 768, 768, 768, 8192, 0, 0);
    // qks[b] = M' @ [q'|k']  (per batch)
    k_gemm<1><<<dim3(12, 8, 8), dim3(256), 0, stream>>>(
        mTb, qkvT, qks, nullptr, 1024, 1536, 1024, 1024, 8192, 1536,
        1024L, 1024L * 1536L);
    // fused attention
    k_attn2<<<dim3(8, 96), dim3(256), 0, stream>>>(qks, qkvT, mbb, attnb);
    // out = attn @ w_out + b_out
    k_gemm<2><<<dim3(6, 64, 1), dim3(256), 0, stream>>>(
        attnb, woutT, out, b_out, 8192, 768, 768, 768, 768, 768, 0, 0);
}